// Round 7
// baseline (1428.047 us; speedup 1.0000x reference)
//
#include <hip/hip_runtime.h>
#include <hip/hip_bf16.h>

#define HIDDEN 3072
#define INTER  8192
#define NTOK   8192   // B*S = 4*2048

typedef __attribute__((ext_vector_type(8))) short bf16x8;
typedef __attribute__((ext_vector_type(16))) float f32x16;

__device__ __forceinline__ void gload_lds16(const void* g, void* l) {
  __builtin_amdgcn_global_load_lds(
      (const __attribute__((address_space(1))) void*)g,
      (__attribute__((address_space(3))) void*)l, 16, 0, 0);
}

__device__ __forceinline__ unsigned short f2bf(float f) {
  unsigned int u = __builtin_bit_cast(unsigned int, f);
  u += 0x7fffu + ((u >> 16) & 1u);   // round-to-nearest-even
  return (unsigned short)(u >> 16);
}

// ---------------- conversion / init kernels ----------------

__global__ void cvt_f32_bf16(const float* __restrict__ in,
                             unsigned short* __restrict__ out, int n4) {
  int i = blockIdx.x * blockDim.x + threadIdx.x;
  if (i >= n4) return;
  float4 v = reinterpret_cast<const float4*>(in)[i];
  ushort4 o;
  o.x = f2bf(v.x); o.y = f2bf(v.y); o.z = f2bf(v.z); o.w = f2bf(v.w);
  reinterpret_cast<ushort4*>(out)[i] = o;
}

__global__ void cvt_i32_bf16(const int* __restrict__ in,
                             unsigned short* __restrict__ out, int n4) {
  int i = blockIdx.x * blockDim.x + threadIdx.x;
  if (i >= n4) return;
  int4 v = reinterpret_cast<const int4*>(in)[i];
  ushort4 o;
  o.x = f2bf((float)v.x); o.y = f2bf((float)v.y);
  o.z = f2bf((float)v.z); o.w = f2bf((float)v.w);
  reinterpret_cast<ushort4*>(out)[i] = o;
}

// W_gu convert with gate/up row interleave at 32-row granularity (matches
// the 32-wide n-fragment of mfma_32x32x16):
// W'-row rowp = 64*(h>>5) + 32*u + (h&31), u=0 gate / 1 up.
// A 64-row wave n-subtile = {gate h-block(32), up h-block(32)} of same h's.
__global__ void cvt_wgu_perm(const int* __restrict__ in,
                             unsigned short* __restrict__ out) {
  int i4 = blockIdx.x * blockDim.x + threadIdx.x;
  const int RW = HIDDEN / 4;   // 768 int4-groups per row
  if (i4 >= 2 * INTER * RW) return;
  int rowp = i4 / RW;
  int col4 = i4 - rowp * RW;
  int h = ((rowp >> 6) << 5) + (rowp & 31);
  int u = (rowp >> 5) & 1;
  int srow = u * INTER + h;
  int4 v = reinterpret_cast<const int4*>(in)[(size_t)srow * RW + col4];
  ushort4 o;
  o.x = f2bf((float)v.x); o.y = f2bf((float)v.y);
  o.z = f2bf((float)v.z); o.w = f2bf((float)v.w);
  reinterpret_cast<ushort4*>(out)[i4] = o;
}

__global__ void zero_out(float* __restrict__ out, int n4) {
  int stride = gridDim.x * blockDim.x;
  for (int i = blockIdx.x * blockDim.x + threadIdx.x; i < n4; i += stride)
    reinterpret_cast<float4*>(out)[i] = make_float4(0.f, 0.f, 0.f, 0.f);
}

// ---------------- 256x256 8-phase GEMM, 32x32x16 MFMA ----------------
// C = A[M=8192][k] * B[N][k]^T, bf16 in, fp32 acc.
// 512 threads = 8 waves (2M x 4N). Per wave: 128x64 out = 4m x 2n tiles of
// 32x32 -> acc[4][2] f32x16 (128 regs, same as before).
// LDS: [parity][op A/B][k-half][256 rows][32 cols] bf16 = 128 KiB.
//
// MFMA 32x32x16 maps (C/D verified m74/m101; A/B = blocked doubling of
// CDNA3 32x32x8, mirroring how the validated 16x16x32 extends 16x16x16):
//   A/B: row = lane&31, k = 8*(lane>>5) + e  (e = 0..7, one bf16x8)
//   C/D: col = lane&31, row = (reg&3) + 8*(reg>>2) + 4*(lane>>5)
// Bank check (swizzle cb = g ^ ((row>>1)&3)): 32-row fragment read puts
// exactly 8 lanes per bank-quad = ds_read_b128 floor -> conflict-free
// (round-6 measured 0 conflicts with the same swizzle family).
//
// Stage schedule + vmcnt ledger IDENTICAL to validated round-5/6:
//   P1 -> B(t+1)kh1   P2 -> A(t+2)kh0   P3 -> B(t+2)kh0   P4 -> A(t+2)kh1
//   steady waits vmcnt(10); tails 8/4/0; prologue 7 stages + vmcnt(10).
//
// KSPLIT: grid = ntmn*KSPLIT blocks; slice k-window = KLEN; MODE 2 epilogue
// atomicAdds into zero-initialized out (2 f32 adds/elem -> order-exact).

template<int STRIDE, int KLEN, int N, int KSPLIT, int MODE>
__global__ __launch_bounds__(512, 2) void gemm8p(
    const unsigned short* __restrict__ A,   // [NTOK][STRIDE]
    const unsigned short* __restrict__ B,   // [N][STRIDE]
    const float* __restrict__ scale,
    void* __restrict__ outv)
{
  constexpr int NT = KLEN / 64;
  __shared__ __align__(16) unsigned short lds[2][2][2][256 * 32];

  const int nbn = N / 256;
  const int ntmn = (NTOK / 256) * nbn;
  const int nwg = ntmn * KSPLIT;            // %8 == 0 for all instantiations
  int bid = blockIdx.x;
  int wg = (bid & 7) * (nwg >> 3) + (bid >> 3);   // XCD-aware bijective swizzle
  const int kslice = wg / ntmn;
  const int local = wg - kslice * ntmn;
  const int bm = (local / nbn) * 256;
  const int bn = (local % nbn) * 256;
  const int koff = kslice * KLEN;

  const int tid  = threadIdx.x;
  const int lane = tid & 63;
  const int wid  = tid >> 6;
  const int wr = wid >> 2;                  // 0..1
  const int wc = wid & 3;                   // 0..3

  // staging coords: chunk = inst*512 + tid; row = chunk>>2, c_l = chunk&3
  const int srow0 = tid >> 2;               // rows 0..127 (inst 0)
  const int srow1 = 128 + (tid >> 2);       // rows 128..255 (inst 1)
  const int scb   = tid & 3;

  const unsigned short* Ab = A + (size_t)bm * STRIDE + koff;
  const unsigned short* Bb = B + (size_t)bn * STRIDE + koff;

  auto stage = [&](const unsigned short* Gb, int op, int tt, int kh) {
    if (tt >= NT) return;
    int p = tt & 1;
    int kc = tt * 64 + kh * 32;
    unsigned short* lbase = &lds[p][op][kh][0];
    gload_lds16(Gb + (size_t)srow0 * STRIDE + kc + ((scb ^ ((srow0 >> 1) & 3)) * 8),
                lbase + (size_t)tid * 8);
    gload_lds16(Gb + (size_t)srow1 * STRIDE + kc + ((scb ^ ((srow1 >> 1) & 3)) * 8),
                lbase + (size_t)(512 + tid) * 8);
  };

  // fragment reads: row = base + (lane&31); chunk g = ks*2 + (lane>>5)
  auto readA = [&](int p, int kh, int m, int ks) -> bf16x8 {
    int row = wr * 128 + m * 32 + (lane & 31);
    int cb = (ks * 2 + (lane >> 5)) ^ ((row >> 1) & 3);
    return *(const bf16x8*)&lds[p][0][kh][row * 32 + cb * 8];
  };
  auto readB = [&](int p, int kh, int n, int ks) -> bf16x8 {
    int row = wc * 64 + n * 32 + (lane & 31);
    int cb = (ks * 2 + (lane >> 5)) ^ ((row >> 1) & 3);
    return *(const bf16x8*)&lds[p][1][kh][row * 32 + cb * 8];
  };

  f32x16 acc[4][2] = {};
  bf16x8 af[4][2];
  bf16x8 b0, b1;

  // prologue: tile 0 fully + tile 1 minus B(1)kh1 (issued at t=0 P1)
  stage(Ab, 0, 0, 0);
  stage(Bb, 1, 0, 0);
  stage(Ab, 0, 0, 1);
  stage(Bb, 1, 0, 1);
  stage(Ab, 0, 1, 0);
  stage(Bb, 1, 1, 0);
  stage(Ab, 0, 1, 1);
  asm volatile("s_waitcnt vmcnt(10)" ::: "memory");
  __builtin_amdgcn_s_barrier();

  for (int t = 0; t < NT; ++t) {
    const int pr = t & 1;
    // ---- phase 1: kh0, n-tile 0 ----
#pragma unroll
    for (int m = 0; m < 4; ++m) {
      af[m][0] = readA(pr, 0, m, 0);
      af[m][1] = readA(pr, 0, m, 1);
    }
    b0 = readB(pr, 0, 0, 0);
    b1 = readB(pr, 0, 0, 1);
    stage(Bb, 1, t + 1, 1);
    __builtin_amdgcn_s_barrier();
    __builtin_amdgcn_s_setprio(1);
#pragma unroll
    for (int m = 0; m < 4; ++m) {
      acc[m][0] = __builtin_amdgcn_mfma_f32_32x32x16_bf16(af[m][0], b0, acc[m][0], 0, 0, 0);
      acc[m][0] = __builtin_amdgcn_mfma_f32_32x32x16_bf16(af[m][1], b1, acc[m][0], 0, 0, 0);
    }
    __builtin_amdgcn_s_setprio(0);
    __builtin_amdgcn_s_barrier();

    // ---- phase 2: kh0, n-tile 1 ----
    b0 = readB(pr, 0, 1, 0);
    b1 = readB(pr, 0, 1, 1);
    stage(Ab, 0, t + 2, 0);
    __builtin_amdgcn_s_barrier();
    __builtin_amdgcn_s_setprio(1);
#pragma unroll
    for (int m = 0; m < 4; ++m) {
      acc[m][1] = __builtin_amdgcn_mfma_f32_32x32x16_bf16(af[m][0], b0, acc[m][1], 0, 0, 0);
      acc[m][1] = __builtin_amdgcn_mfma_f32_32x32x16_bf16(af[m][1], b1, acc[m][1], 0, 0, 0);
    }
    __builtin_amdgcn_s_setprio(0);
    // W2: this tile's kh1 must be landed before P3 (tail-exact per ledger)
    if (t + 2 < NT) {
      asm volatile("s_waitcnt vmcnt(10)" ::: "memory");
    } else if (t + 1 < NT) {
      asm volatile("s_waitcnt vmcnt(8)" ::: "memory");
    } else {
      asm volatile("s_waitcnt vmcnt(0)" ::: "memory");
    }
    __builtin_amdgcn_s_barrier();

    // ---- phase 3: kh1, n-tile 0 ----
#pragma unroll
    for (int m = 0; m < 4; ++m) {
      af[m][0] = readA(pr, 1, m, 0);
      af[m][1] = readA(pr, 1, m, 1);
    }
    b0 = readB(pr, 1, 0, 0);
    b1 = readB(pr, 1, 0, 1);
    stage(Bb, 1, t + 2, 0);
    __builtin_amdgcn_s_barrier();
    __builtin_amdgcn_s_setprio(1);
#pragma unroll
    for (int m = 0; m < 4; ++m) {
      acc[m][0] = __builtin_amdgcn_mfma_f32_32x32x16_bf16(af[m][0], b0, acc[m][0], 0, 0, 0);
      acc[m][0] = __builtin_amdgcn_mfma_f32_32x32x16_bf16(af[m][1], b1, acc[m][0], 0, 0, 0);
    }
    __builtin_amdgcn_s_setprio(0);
    __builtin_amdgcn_s_barrier();

    // ---- phase 4: kh1, n-tile 1 ----
    b0 = readB(pr, 1, 1, 0);
    b1 = readB(pr, 1, 1, 1);
    stage(Ab, 0, t + 2, 1);
    __builtin_amdgcn_s_barrier();
    __builtin_amdgcn_s_setprio(1);
#pragma unroll
    for (int m = 0; m < 4; ++m) {
      acc[m][1] = __builtin_amdgcn_mfma_f32_32x32x16_bf16(af[m][0], b0, acc[m][1], 0, 0, 0);
      acc[m][1] = __builtin_amdgcn_mfma_f32_32x32x16_bf16(af[m][1], b1, acc[m][1], 0, 0, 0);
    }
    __builtin_amdgcn_s_setprio(0);
    // W1: next tile's kh0 must be landed before its P1 (tail-exact)
    if (t + 2 < NT) {
      asm volatile("s_waitcnt vmcnt(10)" ::: "memory");
    } else if (t + 1 < NT) {
      asm volatile("s_waitcnt vmcnt(4)" ::: "memory");
    } else {
      asm volatile("s_waitcnt vmcnt(0)" ::: "memory");
    }
    __builtin_amdgcn_s_barrier();
  }

  // ---- epilogue: 32x32 C/D map col=lane&31, row=(r&3)+8*(r>>2)+4*(lane>>5) ----
  const int ccol  = lane & 31;
  const int crow4 = 4 * (lane >> 5);
  if constexpr (MODE == 1) {
    // SwiGLU: n-tile 0 = gate, n-tile 1 = up (32-granular interleave)
    unsigned short* H = (unsigned short*)outv;     // [NTOK][INTER]
    const int hcol = (bn >> 1) + wc * 32 + ccol;
    const float sg = scale[hcol];
    const float su = scale[INTER + hcol];
#pragma unroll
    for (int m = 0; m < 4; ++m) {
#pragma unroll
      for (int r = 0; r < 16; ++r) {
        int row = bm + wr * 128 + m * 32 + (r & 3) + 8 * (r >> 2) + crow4;
        float g = acc[m][0][r] * sg;
        float u = acc[m][1][r] * su;
        float s = g / (1.0f + __expf(-g));         // silu
        H[(size_t)row * INTER + hcol] = f2bf(u * s);
      }
    }
  } else {
    // split-K atomic accumulate into zero-initialized f32 out
    float* O = (float*)outv;                       // [NTOK][N]
#pragma unroll
    for (int n = 0; n < 2; ++n) {
      int col = bn + wc * 64 + n * 32 + ccol;
      float sc = scale[col];
#pragma unroll
      for (int m = 0; m < 4; ++m) {
#pragma unroll
        for (int r = 0; r < 16; ++r) {
          int row = bm + wr * 128 + m * 32 + (r & 3) + 8 * (r >> 2) + crow4;
          atomicAdd(&O[(size_t)row * N + col], acc[m][n][r] * sc);
        }
      }
    }
  }
}

// ---------------- launch ----------------

extern "C" void kernel_launch(void* const* d_in, const int* in_sizes, int n_in,
                              void* d_out, int out_size, void* d_ws, size_t ws_size,
                              hipStream_t stream) {
  (void)in_sizes; (void)n_in; (void)out_size; (void)ws_size;

  const float* hidden = (const float*)d_in[0];   // [NTOK][HIDDEN] f32
  const int*   guq    = (const int*)d_in[1];     // [2*INTER][HIDDEN] i32
  const float* gus    = (const float*)d_in[2];   // [2*INTER]
  const int*   dwq    = (const int*)d_in[3];     // [HIDDEN][INTER] i32
  const float* dsc    = (const float*)d_in[4];   // [HIDDEN]
  float* out = (float*)d_out;

  char* ws = (char*)d_ws;
  unsigned short* xb  = (unsigned short*)(ws);                      // 50,331,648 B
  unsigned short* wgu = (unsigned short*)(ws + 50331648ull);        // 100,663,296 B (permuted)
  unsigned short* wd  = (unsigned short*)(ws + 150994944ull);       // 50,331,648 B
  unsigned short* hb  = (unsigned short*)(ws + 201326592ull);       // 134,217,728 B
  // total ws use: 335,544,320 B

  {
    int n4 = NTOK * HIDDEN / 4;
    cvt_f32_bf16<<<(n4 + 255) / 256, 256, 0, stream>>>(hidden, xb, n4);
  }
  {
    int n4 = 2 * INTER * HIDDEN / 4;
    cvt_wgu_perm<<<(n4 + 255) / 256, 256, 0, stream>>>(guq, wgu);
  }
  {
    int n4 = HIDDEN * INTER / 4;
    cvt_i32_bf16<<<(n4 + 255) / 256, 256, 0, stream>>>(dwq, wd, n4);
  }
  // zero d_out for the split-K atomic accumulate (every call: determinism)
  zero_out<<<2048, 256, 0, stream>>>(out, NTOK * HIDDEN / 4);

  // GEMM1+SwiGLU: [8192 x 16384] over K=3072, writes H bf16 [8192][8192]
  gemm8p<HIDDEN, HIDDEN, 2 * INTER, 1, 1>
      <<<(NTOK / 256) * (2 * INTER / 256), 512, 0, stream>>>(xb, wgu, gus, hb);
  // GEMM2: [8192 x 3072] over K=8192, split-K=2 (grid 768 = 3/CU balanced)
  gemm8p<INTER, INTER / 2, HIDDEN, 2, 2>
      <<<(NTOK / 256) * (HIDDEN / 256) * 2, 512, 0, stream>>>(hb, wd, dsc, out);
}

// Round 8
// 1318.461 us; speedup vs baseline: 1.0831x; 1.0831x over previous
//
#include <hip/hip_runtime.h>
#include <hip/hip_bf16.h>

#define HIDDEN 3072
#define INTER  8192
#define NTOK   8192   // B*S = 4*2048

typedef __attribute__((ext_vector_type(8))) short bf16x8;
typedef __attribute__((ext_vector_type(4))) float f32x4;

__device__ __forceinline__ void gload_lds16(const void* g, void* l) {
  __builtin_amdgcn_global_load_lds(
      (const __attribute__((address_space(1))) void*)g,
      (__attribute__((address_space(3))) void*)l, 16, 0, 0);
}

__device__ __forceinline__ unsigned short f2bf(float f) {
  unsigned int u = __builtin_bit_cast(unsigned int, f);
  u += 0x7fffu + ((u >> 16) & 1u);   // round-to-nearest-even
  return (unsigned short)(u >> 16);
}

// ---------------- conversion / init kernels ----------------

__global__ void cvt_f32_bf16(const float* __restrict__ in,
                             unsigned short* __restrict__ out, int n4) {
  int i = blockIdx.x * blockDim.x + threadIdx.x;
  if (i >= n4) return;
  float4 v = reinterpret_cast<const float4*>(in)[i];
  ushort4 o;
  o.x = f2bf(v.x); o.y = f2bf(v.y); o.z = f2bf(v.z); o.w = f2bf(v.w);
  reinterpret_cast<ushort4*>(out)[i] = o;
}

__global__ void cvt_i32_bf16(const int* __restrict__ in,
                             unsigned short* __restrict__ out, int n4) {
  int i = blockIdx.x * blockDim.x + threadIdx.x;
  if (i >= n4) return;
  int4 v = reinterpret_cast<const int4*>(in)[i];
  ushort4 o;
  o.x = f2bf((float)v.x); o.y = f2bf((float)v.y);
  o.z = f2bf((float)v.z); o.w = f2bf((float)v.w);
  reinterpret_cast<ushort4*>(out)[i] = o;
}

// W_gu convert with gate/up row interleave at 16-row granularity (round-6):
// W'-row rowp = 32*(c>>4) + 16*u + (c&15), u=0 gate / 1 up.
__global__ void cvt_wgu_perm(const int* __restrict__ in,
                             unsigned short* __restrict__ out) {
  int i4 = blockIdx.x * blockDim.x + threadIdx.x;
  const int RW = HIDDEN / 4;   // 768 int4-groups per row
  if (i4 >= 2 * INTER * RW) return;
  int rowp = i4 / RW;
  int col4 = i4 - rowp * RW;
  int c = ((rowp >> 5) << 4) + (rowp & 15);
  int u = (rowp >> 4) & 1;
  int srow = u * INTER + c;
  int4 v = reinterpret_cast<const int4*>(in)[(size_t)srow * RW + col4];
  ushort4 o;
  o.x = f2bf((float)v.x); o.y = f2bf((float)v.y);
  o.z = f2bf((float)v.z); o.w = f2bf((float)v.w);
  reinterpret_cast<ushort4*>(out)[i4] = o;
}

__global__ void zero_out(float* __restrict__ out, int n4) {
  int stride = gridDim.x * blockDim.x;
  for (int i = blockIdx.x * blockDim.x + threadIdx.x; i < n4; i += stride)
    reinterpret_cast<float4*>(out)[i] = make_float4(0.f, 0.f, 0.f, 0.f);
}

// ---------------- 256x256 8-phase GEMM, 16x16x32 MFMA ----------------
// Round-8 = round-4's VALIDATED stage schedule/ledger (lookahead-1)
//         + round-6's VALIDATED conflict-free swizzle (measured 0 conflicts)
//         + KSPLIT template (round-7-validated atomicAdd mechanism).
//
// 512 threads = 8 waves (2M x 4N). Per wave: 128x64 out = acc[8][4] f32x4.
// LDS: [parity][op A/B][k-half][256 rows][32 cols] bf16 = 128 KiB.
//
// Swizzle s(row) = (row>>1)&3 at 16B-chunk granularity, involution on both
// sides (inverse-swizzled global source in stage, swizzled cb on read).
// A 16-row fragment read hits each bank exactly 8x = ds_read_b128 floor.
//
// Stage schedule (lookahead-1, round-4):
//   P1 -> A(t+1)kh0   P2 -> B(t+1)kh0   P3 -> A(t+1)kh1   P4 -> B(t+1)kh1
// vmcnt ledger (2 loads/stage): entering tile t: 4 outstanding
// {A(t)kh1,B(t)kh1}. P2-end: 8 outstanding -> vmcnt(4) drains t's kh1
// (tail t=NT-1: only 4 outstanding -> vmcnt(0)). P4-end: vmcnt(4) drains
// (t+1)'s kh0. Prologue: 4 stages + vmcnt(4).

template<int STRIDE, int KLEN, int N, int KSPLIT, int MODE>
__global__ __launch_bounds__(512, 2) void gemm8p(
    const unsigned short* __restrict__ A,   // [NTOK][STRIDE]
    const unsigned short* __restrict__ B,   // [N][STRIDE]
    const float* __restrict__ scale,
    void* __restrict__ outv)
{
  constexpr int NT = KLEN / 64;
  __shared__ __align__(16) unsigned short lds[2][2][2][256 * 32];

  const int nbn = N / 256;
  const int ntmn = (NTOK / 256) * nbn;
  const int nwg = ntmn * KSPLIT;            // %8 == 0 for all instantiations
  int bid = blockIdx.x;
  int wg = (bid & 7) * (nwg >> 3) + (bid >> 3);   // XCD-aware bijective swizzle
  const int kslice = wg / ntmn;
  const int local = wg - kslice * ntmn;
  const int bm = (local / nbn) * 256;
  const int bn = (local % nbn) * 256;
  const int koff = kslice * KLEN;

  const int tid  = threadIdx.x;
  const int lane = tid & 63;
  const int wid  = tid >> 6;
  const int wr = wid >> 2;                  // 0..1
  const int wc = wid & 3;                   // 0..3

  // staging coords: chunk = inst*512 + tid; row = chunk>>2, c_l = chunk&3
  const int srow0 = tid >> 2;               // rows 0..127 (inst 0)
  const int srow1 = 128 + (tid >> 2);       // rows 128..255 (inst 1)
  const int scb   = tid & 3;

  const unsigned short* Ab = A + (size_t)bm * STRIDE + koff;
  const unsigned short* Bb = B + (size_t)bn * STRIDE + koff;

  auto stage = [&](const unsigned short* Gb, int op, int tt, int kh) {
    if (tt >= NT) return;
    int p = tt & 1;
    int kc = tt * 64 + kh * 32;
    unsigned short* lbase = &lds[p][op][kh][0];
    gload_lds16(Gb + (size_t)srow0 * STRIDE + kc + ((scb ^ ((srow0 >> 1) & 3)) * 8),
                lbase + (size_t)tid * 8);
    gload_lds16(Gb + (size_t)srow1 * STRIDE + kc + ((scb ^ ((srow1 >> 1) & 3)) * 8),
                lbase + (size_t)(512 + tid) * 8);
  };

  auto readA = [&](int p, int kh, int m) -> bf16x8 {
    int row = wr * 128 + m * 16 + (lane & 15);
    int cb = (lane >> 4) ^ ((row >> 1) & 3);
    return *(const bf16x8*)&lds[p][0][kh][row * 32 + cb * 8];
  };
  auto readB = [&](int p, int kh, int n) -> bf16x8 {
    int row = wc * 64 + n * 16 + (lane & 15);
    int cb = (lane >> 4) ^ ((row >> 1) & 3);
    return *(const bf16x8*)&lds[p][1][kh][row * 32 + cb * 8];
  };

  f32x4 acc[8][4] = {};
  bf16x8 af[8];

  // prologue: tile 0's 4 half-tiles; vmcnt(4) -> A0kh0, B0kh0 landed
  stage(Ab, 0, 0, 0);
  stage(Bb, 1, 0, 0);
  stage(Ab, 0, 0, 1);
  stage(Bb, 1, 0, 1);
  asm volatile("s_waitcnt vmcnt(4)" ::: "memory");
  __builtin_amdgcn_s_barrier();

  for (int t = 0; t < NT; ++t) {
    const int pr = t & 1;
    // ---- phase 1: kh0, n-frags 0,1 ----
#pragma unroll
    for (int m = 0; m < 8; ++m) af[m] = readA(pr, 0, m);
    bf16x8 b0 = readB(pr, 0, 0);
    bf16x8 b1 = readB(pr, 0, 1);
    stage(Ab, 0, t + 1, 0);
    __builtin_amdgcn_s_barrier();
    __builtin_amdgcn_s_setprio(1);
#pragma unroll
    for (int m = 0; m < 8; ++m) {
      acc[m][0] = __builtin_amdgcn_mfma_f32_16x16x32_bf16(af[m], b0, acc[m][0], 0, 0, 0);
      acc[m][1] = __builtin_amdgcn_mfma_f32_16x16x32_bf16(af[m], b1, acc[m][1], 0, 0, 0);
    }
    __builtin_amdgcn_s_setprio(0);
    __builtin_amdgcn_s_barrier();

    // ---- phase 2: kh0, n-frags 2,3 ----
    b0 = readB(pr, 0, 2);
    b1 = readB(pr, 0, 3);
    stage(Bb, 1, t + 1, 0);
    __builtin_amdgcn_s_barrier();
    __builtin_amdgcn_s_setprio(1);
#pragma unroll
    for (int m = 0; m < 8; ++m) {
      acc[m][2] = __builtin_amdgcn_mfma_f32_16x16x32_bf16(af[m], b0, acc[m][2], 0, 0, 0);
      acc[m][3] = __builtin_amdgcn_mfma_f32_16x16x32_bf16(af[m], b1, acc[m][3], 0, 0, 0);
    }
    __builtin_amdgcn_s_setprio(0);
    // W2: this tile's kh1 must be landed before P3 (tail-exact per ledger)
    if (t + 1 < NT) {
      asm volatile("s_waitcnt vmcnt(4)" ::: "memory");
    } else {
      asm volatile("s_waitcnt vmcnt(0)" ::: "memory");
    }
    __builtin_amdgcn_s_barrier();

    // ---- phase 3: kh1, n-frags 0,1 ----
#pragma unroll
    for (int m = 0; m < 8; ++m) af[m] = readA(pr, 1, m);
    b0 = readB(pr, 1, 0);
    b1 = readB(pr, 1, 1);
    stage(Ab, 0, t + 1, 1);
    __builtin_amdgcn_s_barrier();
    __builtin_amdgcn_s_setprio(1);
#pragma unroll
    for (int m = 0; m < 8; ++m) {
      acc[m][0] = __builtin_amdgcn_mfma_f32_16x16x32_bf16(af[m], b0, acc[m][0], 0, 0, 0);
      acc[m][1] = __builtin_amdgcn_mfma_f32_16x16x32_bf16(af[m], b1, acc[m][1], 0, 0, 0);
    }
    __builtin_amdgcn_s_setprio(0);
    __builtin_amdgcn_s_barrier();

    // ---- phase 4: kh1, n-frags 2,3 ----
    b0 = readB(pr, 1, 2);
    b1 = readB(pr, 1, 3);
    stage(Bb, 1, t + 1, 1);
    __builtin_amdgcn_s_barrier();
    __builtin_amdgcn_s_setprio(1);
#pragma unroll
    for (int m = 0; m < 8; ++m) {
      acc[m][2] = __builtin_amdgcn_mfma_f32_16x16x32_bf16(af[m], b0, acc[m][2], 0, 0, 0);
      acc[m][3] = __builtin_amdgcn_mfma_f32_16x16x32_bf16(af[m], b1, acc[m][3], 0, 0, 0);
    }
    __builtin_amdgcn_s_setprio(0);
    // W1: next tile's kh0 landed before its P1 (no-op on last tile)
    asm volatile("s_waitcnt vmcnt(4)" ::: "memory");
    __builtin_amdgcn_s_barrier();
  }

  // ---- epilogue: C/D layout col=lane&15, row=(lane>>4)*4+j ----
  const int crow0 = (lane >> 4) * 4;
  const int ccol  = lane & 15;
  if constexpr (MODE == 1) {
    // SwiGLU: n-frags (gate,up,gate,up) via 16-granular W interleave
    unsigned short* H = (unsigned short*)outv;     // [NTOK][INTER]
    const int hbase = (bn >> 1) + wc * 32;
#pragma unroll
    for (int np = 0; np < 2; ++np) {
      int hcol = hbase + np * 16 + ccol;
      float sg = scale[hcol];
      float su = scale[INTER + hcol];
#pragma unroll
      for (int m = 0; m < 8; ++m) {
#pragma unroll
        for (int j = 0; j < 4; ++j) {
          int row = bm + wr * 128 + m * 16 + crow0 + j;
          float g = acc[m][2 * np + 0][j] * sg;
          float u = acc[m][2 * np + 1][j] * su;
          float s = g / (1.0f + __expf(-g));       // silu
          H[(size_t)row * INTER + hcol] = f2bf(u * s);
        }
      }
    }
  } else {
    // split-K atomic accumulate into zero-initialized f32 out
    float* O = (float*)outv;                       // [NTOK][N]
#pragma unroll
    for (int n = 0; n < 4; ++n) {
      int col = bn + wc * 64 + n * 16 + ccol;
      float sc = scale[col];
#pragma unroll
      for (int m = 0; m < 8; ++m) {
#pragma unroll
        for (int j = 0; j < 4; ++j) {
          int row = bm + wr * 128 + m * 16 + crow0 + j;
          atomicAdd(&O[(size_t)row * N + col], acc[m][n][j] * sc);
        }
      }
    }
  }
}

// ---------------- launch ----------------

extern "C" void kernel_launch(void* const* d_in, const int* in_sizes, int n_in,
                              void* d_out, int out_size, void* d_ws, size_t ws_size,
                              hipStream_t stream) {
  (void)in_sizes; (void)n_in; (void)out_size; (void)ws_size;

  const float* hidden = (const float*)d_in[0];   // [NTOK][HIDDEN] f32
  const int*   guq    = (const int*)d_in[1];     // [2*INTER][HIDDEN] i32
  const float* gus    = (const float*)d_in[2];   // [2*INTER]
  const int*   dwq    = (const int*)d_in[3];     // [HIDDEN][INTER] i32
  const float* dsc    = (const float*)d_in[4];   // [HIDDEN]
  float* out = (float*)d_out;

  char* ws = (char*)d_ws;
  unsigned short* xb  = (unsigned short*)(ws);                      // 50,331,648 B
  unsigned short* wgu = (unsigned short*)(ws + 50331648ull);        // 100,663,296 B (permuted)
  unsigned short* wd  = (unsigned short*)(ws + 150994944ull);       // 50,331,648 B
  unsigned short* hb  = (unsigned short*)(ws + 201326592ull);       // 134,217,728 B
  // total ws use: 335,544,320 B

  {
    int n4 = NTOK * HIDDEN / 4;
    cvt_f32_bf16<<<(n4 + 255) / 256, 256, 0, stream>>>(hidden, xb, n4);
  }
  {
    int n4 = 2 * INTER * HIDDEN / 4;
    cvt_wgu_perm<<<(n4 + 255) / 256, 256, 0, stream>>>(guq, wgu);
  }
  {
    int n4 = HIDDEN * INTER / 4;
    cvt_i32_bf16<<<(n4 + 255) / 256, 256, 0, stream>>>(dwq, wd, n4);
  }
  // zero d_out for the split-K atomic accumulate (every call: determinism)
  zero_out<<<2048, 256, 0, stream>>>(out, NTOK * HIDDEN / 4);

  // GEMM1+SwiGLU: [8192 x 16384] over K=3072, writes H bf16 [8192][8192]
  gemm8p<HIDDEN, HIDDEN, 2 * INTER, 1, 1>
      <<<(NTOK / 256) * (2 * INTER / 256), 512, 0, stream>>>(xb, wgu, gus, hb);
  // GEMM2: [8192 x 3072] over K=8192, split-K=2 (grid 768 = 3 exact rounds)
  gemm8p<INTER, INTER / 2, HIDDEN, 2, 2>
      <<<(NTOK / 256) * (HIDDEN / 256) * 2, 512, 0, stream>>>(hb, wd, dsc, out);
}

// Round 9
// 1253.172 us; speedup vs baseline: 1.1395x; 1.0521x over previous
//
#include <hip/hip_runtime.h>
#include <hip/hip_bf16.h>

#define HIDDEN 3072
#define INTER  8192
#define NTOK   8192   // B*S = 4*2048

typedef __attribute__((ext_vector_type(8))) short bf16x8;
typedef __attribute__((ext_vector_type(4))) float f32x4;

__device__ __forceinline__ void gload_lds16(const void* g, void* l) {
  __builtin_amdgcn_global_load_lds(
      (const __attribute__((address_space(1))) void*)g,
      (__attribute__((address_space(3))) void*)l, 16, 0, 0);
}

__device__ __forceinline__ unsigned short f2bf(float f) {
  unsigned int u = __builtin_bit_cast(unsigned int, f);
  u += 0x7fffu + ((u >> 16) & 1u);   // round-to-nearest-even
  return (unsigned short)(u >> 16);
}

// ---------------- conversion kernels ----------------

__global__ void cvt_f32_bf16(const float* __restrict__ in,
                             unsigned short* __restrict__ out, int n4) {
  int i = blockIdx.x * blockDim.x + threadIdx.x;
  if (i >= n4) return;
  float4 v = reinterpret_cast<const float4*>(in)[i];
  ushort4 o;
  o.x = f2bf(v.x); o.y = f2bf(v.y); o.z = f2bf(v.z); o.w = f2bf(v.w);
  reinterpret_cast<ushort4*>(out)[i] = o;
}

__global__ void cvt_i32_bf16(const int* __restrict__ in,
                             unsigned short* __restrict__ out, int n4) {
  int i = blockIdx.x * blockDim.x + threadIdx.x;
  if (i >= n4) return;
  int4 v = reinterpret_cast<const int4*>(in)[i];
  ushort4 o;
  o.x = f2bf((float)v.x); o.y = f2bf((float)v.y);
  o.z = f2bf((float)v.z); o.w = f2bf((float)v.w);
  reinterpret_cast<ushort4*>(out)[i] = o;
}

// W_gu convert with gate/up row interleave at 16-row granularity:
// W'-row rowp = 32*(c>>4) + 16*u + (c&15), u=0 gate / 1 up.
__global__ void cvt_wgu_perm(const int* __restrict__ in,
                             unsigned short* __restrict__ out) {
  int i4 = blockIdx.x * blockDim.x + threadIdx.x;
  const int RW = HIDDEN / 4;   // 768 int4-groups per row
  if (i4 >= 2 * INTER * RW) return;
  int rowp = i4 / RW;
  int col4 = i4 - rowp * RW;
  int c = ((rowp >> 5) << 4) + (rowp & 15);
  int u = (rowp >> 4) & 1;
  int srow = u * INTER + c;
  int4 v = reinterpret_cast<const int4*>(in)[(size_t)srow * RW + col4];
  ushort4 o;
  o.x = f2bf((float)v.x); o.y = f2bf((float)v.y);
  o.z = f2bf((float)v.z); o.w = f2bf((float)v.w);
  reinterpret_cast<ushort4*>(out)[i4] = o;
}

// ---------------- 256x256 GEMM, 16x16x32 MFMA, 2-barrier/K-tile ----------------
// Round-9: R8's validated staging/swizzle/vmcnt ledger, with
//  (1) barriers reduced to the 2 correctness-critical ones per K-tile
//      (after W2 and after W1). The other 6 ordered nothing: MFMA->own-wave
//      ds_read is a register dependence. Kept barriers still guarantee
//      "all waves drained own loads" => "all stage-writes landed" (RAW) and
//      fence the parity buffer against next-tile stages (WAR).
//      Waves now drift across a 2-phase window -> one wave's ds_reads
//      overlap another's MFMA (the measured missing ~50%: wall 4900cy =
//      MFMA 2485 + reads ~2300 with zero overlap).
//  (2) reads balanced 8/4/8/4: all 4 B-frags held in regs; MFMA split by
//      m-half (P1: m0..3, P2: m4..7). acc meaning unchanged.
//
// Stage schedule + ledger (VALIDATED R8): per tile t:
//   P1 stage A(t+1)k0, P2 stage B(t+1)k0, P3 stage A(t+1)k1, P4 stage B(t+1)k1
//   entering t: 4 outstanding {A(t)k1,B(t)k1}; P2-end: 8 -> vmcnt(4) drains
//   t's kh1 (tail t=NT-1: vmcnt(0)); P4-end: vmcnt(4) drains (t+1)'s kh0.
// Swizzle (VALIDATED R6, 0 conflicts): chunk cb ^= (row>>1)&3, involution on
// both sides (inverse-swizzled global source; swizzled read).

template<int K, int N, int MODE>
__global__ __launch_bounds__(512, 2) void gemm8p(
    const unsigned short* __restrict__ A,   // [NTOK][K]
    const unsigned short* __restrict__ B,   // [N][K]
    const float* __restrict__ scale,
    void* __restrict__ outv)
{
  constexpr int NT = K / 64;
  __shared__ __align__(16) unsigned short lds[2][2][2][256 * 32];

  const int nbn = N / 256;
  const int nwg = (NTOK / 256) * nbn;       // %8 == 0 for both instantiations
  int bid = blockIdx.x;
  int wg = (bid & 7) * (nwg >> 3) + (bid >> 3);   // XCD-aware bijective swizzle
  const int bm = (wg / nbn) * 256;
  const int bn = (wg % nbn) * 256;

  const int tid  = threadIdx.x;
  const int lane = tid & 63;
  const int wid  = tid >> 6;
  const int wr = wid >> 2;                  // 0..1
  const int wc = wid & 3;                   // 0..3

  // staging coords: chunk = inst*512 + tid; row = chunk>>2, c_l = chunk&3
  const int srow0 = tid >> 2;               // rows 0..127 (inst 0)
  const int srow1 = 128 + (tid >> 2);       // rows 128..255 (inst 1)
  const int scb   = tid & 3;

  const unsigned short* Ab = A + (size_t)bm * K;
  const unsigned short* Bb = B + (size_t)bn * K;

  auto stage = [&](const unsigned short* Gb, int op, int tt, int kh) {
    if (tt >= NT) return;
    int p = tt & 1;
    int kc = tt * 64 + kh * 32;
    unsigned short* lbase = &lds[p][op][kh][0];
    gload_lds16(Gb + (size_t)srow0 * K + kc + ((scb ^ ((srow0 >> 1) & 3)) * 8),
                lbase + (size_t)tid * 8);
    gload_lds16(Gb + (size_t)srow1 * K + kc + ((scb ^ ((srow1 >> 1) & 3)) * 8),
                lbase + (size_t)(512 + tid) * 8);
  };

  auto readA = [&](int p, int kh, int m) -> bf16x8 {
    int row = wr * 128 + m * 16 + (lane & 15);
    int cb = (lane >> 4) ^ ((row >> 1) & 3);
    return *(const bf16x8*)&lds[p][0][kh][row * 32 + cb * 8];
  };
  auto readB = [&](int p, int kh, int n) -> bf16x8 {
    int row = wc * 64 + n * 16 + (lane & 15);
    int cb = (lane >> 4) ^ ((row >> 1) & 3);
    return *(const bf16x8*)&lds[p][1][kh][row * 32 + cb * 8];
  };

  f32x4 acc[8][4] = {};
  bf16x8 af[4], ag[4], b[4];

  // prologue: tile 0's 4 half-tiles; vmcnt(4) -> A0kh0, B0kh0 landed
  stage(Ab, 0, 0, 0);
  stage(Bb, 1, 0, 0);
  stage(Ab, 0, 0, 1);
  stage(Bb, 1, 0, 1);
  asm volatile("s_waitcnt vmcnt(4)" ::: "memory");
  __builtin_amdgcn_s_barrier();

  for (int t = 0; t < NT; ++t) {
    const int pr = t & 1;

    // ---- phase 1: kh0, m-half 0 (reads: 4 A + 4 B) ----
#pragma unroll
    for (int m = 0; m < 4; ++m) af[m] = readA(pr, 0, m);
#pragma unroll
    for (int n = 0; n < 4; ++n) b[n] = readB(pr, 0, n);
    stage(Ab, 0, t + 1, 0);
    __builtin_amdgcn_s_setprio(1);
#pragma unroll
    for (int m = 0; m < 4; ++m)
#pragma unroll
      for (int n = 0; n < 4; ++n)
        acc[m][n] = __builtin_amdgcn_mfma_f32_16x16x32_bf16(af[m], b[n], acc[m][n], 0, 0, 0);
    __builtin_amdgcn_s_setprio(0);

    // ---- phase 2: kh0, m-half 1 (reads: 4 A) ----
#pragma unroll
    for (int m = 0; m < 4; ++m) ag[m] = readA(pr, 0, m + 4);
    stage(Bb, 1, t + 1, 0);
    __builtin_amdgcn_s_setprio(1);
#pragma unroll
    for (int m = 0; m < 4; ++m)
#pragma unroll
      for (int n = 0; n < 4; ++n)
        acc[m + 4][n] = __builtin_amdgcn_mfma_f32_16x16x32_bf16(ag[m], b[n], acc[m + 4][n], 0, 0, 0);
    __builtin_amdgcn_s_setprio(0);
    // W2 + barrier (correctness): all waves' kh1-of-t loads landed
    if (t + 1 < NT) {
      asm volatile("s_waitcnt vmcnt(4)" ::: "memory");
    } else {
      asm volatile("s_waitcnt vmcnt(0)" ::: "memory");
    }
    __builtin_amdgcn_s_barrier();

    // ---- phase 3: kh1, m-half 0 ----
#pragma unroll
    for (int m = 0; m < 4; ++m) af[m] = readA(pr, 1, m);
#pragma unroll
    for (int n = 0; n < 4; ++n) b[n] = readB(pr, 1, n);
    stage(Ab, 0, t + 1, 1);
    __builtin_amdgcn_s_setprio(1);
#pragma unroll
    for (int m = 0; m < 4; ++m)
#pragma unroll
      for (int n = 0; n < 4; ++n)
        acc[m][n] = __builtin_amdgcn_mfma_f32_16x16x32_bf16(af[m], b[n], acc[m][n], 0, 0, 0);
    __builtin_amdgcn_s_setprio(0);

    // ---- phase 4: kh1, m-half 1 ----
#pragma unroll
    for (int m = 0; m < 4; ++m) ag[m] = readA(pr, 1, m + 4);
    stage(Bb, 1, t + 1, 1);
    __builtin_amdgcn_s_setprio(1);
#pragma unroll
    for (int m = 0; m < 4; ++m)
#pragma unroll
      for (int n = 0; n < 4; ++n)
        acc[m + 4][n] = __builtin_amdgcn_mfma_f32_16x16x32_bf16(ag[m], b[n], acc[m + 4][n], 0, 0, 0);
    __builtin_amdgcn_s_setprio(0);
    // W1 + barrier (correctness): all waves' kh0-of-(t+1) loads landed;
    // also the WAR fence for next tile's stages into the read parity.
    asm volatile("s_waitcnt vmcnt(4)" ::: "memory");
    __builtin_amdgcn_s_barrier();
  }

  // ---- epilogue: C/D layout col=lane&15, row=(lane>>4)*4+j ----
  const int crow0 = (lane >> 4) * 4;
  const int ccol  = lane & 15;
  if constexpr (MODE == 1) {
    // SwiGLU: n-frags (gate,up,gate,up) via 16-granular W interleave
    unsigned short* H = (unsigned short*)outv;     // [NTOK][INTER]
    const int hbase = (bn >> 1) + wc * 32;
#pragma unroll
    for (int np = 0; np < 2; ++np) {
      int hcol = hbase + np * 16 + ccol;
      float sg = scale[hcol];
      float su = scale[INTER + hcol];
#pragma unroll
      for (int m = 0; m < 8; ++m) {
#pragma unroll
        for (int j = 0; j < 4; ++j) {
          int row = bm + wr * 128 + m * 16 + crow0 + j;
          float g = acc[m][2 * np + 0][j] * sg;
          float u = acc[m][2 * np + 1][j] * su;
          float s = g / (1.0f + __expf(-g));       // silu
          H[(size_t)row * INTER + hcol] = f2bf(u * s);
        }
      }
    }
  } else {
    float* O = (float*)outv;                       // [NTOK][N]
#pragma unroll
    for (int n = 0; n < 4; ++n) {
      int col = bn + wc * 64 + n * 16 + ccol;
      float sc = scale[col];
#pragma unroll
      for (int m = 0; m < 8; ++m) {
#pragma unroll
        for (int j = 0; j < 4; ++j) {
          int row = bm + wr * 128 + m * 16 + crow0 + j;
          O[(size_t)row * N + col] = acc[m][n][j] * sc;
        }
      }
    }
  }
}

// ---------------- launch ----------------

extern "C" void kernel_launch(void* const* d_in, const int* in_sizes, int n_in,
                              void* d_out, int out_size, void* d_ws, size_t ws_size,
                              hipStream_t stream) {
  (void)in_sizes; (void)n_in; (void)out_size; (void)ws_size;

  const float* hidden = (const float*)d_in[0];   // [NTOK][HIDDEN] f32
  const int*   guq    = (const int*)d_in[1];     // [2*INTER][HIDDEN] i32
  const float* gus    = (const float*)d_in[2];   // [2*INTER]
  const int*   dwq    = (const int*)d_in[3];     // [HIDDEN][INTER] i32
  const float* dsc    = (const float*)d_in[4];   // [HIDDEN]
  float* out = (float*)d_out;

  char* ws = (char*)d_ws;
  unsigned short* xb  = (unsigned short*)(ws);                      // 50,331,648 B
  unsigned short* wgu = (unsigned short*)(ws + 50331648ull);        // 100,663,296 B (permuted)
  unsigned short* wd  = (unsigned short*)(ws + 150994944ull);       // 50,331,648 B
  unsigned short* hb  = (unsigned short*)(ws + 201326592ull);       // 134,217,728 B
  // total ws use: 335,544,320 B

  {
    int n4 = NTOK * HIDDEN / 4;
    cvt_f32_bf16<<<(n4 + 255) / 256, 256, 0, stream>>>(hidden, xb, n4);
  }
  {
    int n4 = 2 * INTER * HIDDEN / 4;
    cvt_wgu_perm<<<(n4 + 255) / 256, 256, 0, stream>>>(guq, wgu);
  }
  {
    int n4 = HIDDEN * INTER / 4;
    cvt_i32_bf16<<<(n4 + 255) / 256, 256, 0, stream>>>(dwq, wd, n4);
  }

  // GEMM1+SwiGLU: [8192 x 16384] over K=3072, writes H bf16 [8192][8192]
  gemm8p<HIDDEN, 2 * INTER, 1>
      <<<(NTOK / 256) * (2 * INTER / 256), 512, 0, stream>>>(xb, wgu, gus, hb);
  // GEMM2: [8192 x 3072] over K=8192, full-K, plain f32 store
  gemm8p<INTER, HIDDEN, 2>
      <<<(NTOK / 256) * (HIDDEN / 256), 512, 0, stream>>>(hb, wd, dsc, out);
}

// Round 10
// 1241.181 us; speedup vs baseline: 1.1506x; 1.0097x over previous
//
#include <hip/hip_runtime.h>
#include <hip/hip_bf16.h>

#define HIDDEN 3072
#define INTER  8192
#define NTOK   8192   // B*S = 4*2048

typedef __attribute__((ext_vector_type(8))) short bf16x8;
typedef __attribute__((ext_vector_type(4))) float f32x4;

__device__ __forceinline__ void gload_lds16(const void* g, void* l) {
  __builtin_amdgcn_global_load_lds(
      (const __attribute__((address_space(1))) void*)g,
      (__attribute__((address_space(3))) void*)l, 16, 0, 0);
}

__device__ __forceinline__ unsigned short f2bf(float f) {
  unsigned int u = __builtin_bit_cast(unsigned int, f);
  u += 0x7fffu + ((u >> 16) & 1u);   // round-to-nearest-even
  return (unsigned short)(u >> 16);
}

// ---------------- conversion kernels ----------------

__global__ void cvt_f32_bf16(const float* __restrict__ in,
                             unsigned short* __restrict__ out, int n4) {
  int i = blockIdx.x * blockDim.x + threadIdx.x;
  if (i >= n4) return;
  float4 v = reinterpret_cast<const float4*>(in)[i];
  ushort4 o;
  o.x = f2bf(v.x); o.y = f2bf(v.y); o.z = f2bf(v.z); o.w = f2bf(v.w);
  reinterpret_cast<ushort4*>(out)[i] = o;
}

__global__ void cvt_i32_bf16(const int* __restrict__ in,
                             unsigned short* __restrict__ out, int n4) {
  int i = blockIdx.x * blockDim.x + threadIdx.x;
  if (i >= n4) return;
  int4 v = reinterpret_cast<const int4*>(in)[i];
  ushort4 o;
  o.x = f2bf((float)v.x); o.y = f2bf((float)v.y);
  o.z = f2bf((float)v.z); o.w = f2bf((float)v.w);
  reinterpret_cast<ushort4*>(out)[i] = o;
}

// W_gu convert with gate/up row interleave at 16-row granularity:
// W'-row rowp = 32*(c>>4) + 16*u + (c&15), u=0 gate / 1 up.
__global__ void cvt_wgu_perm(const int* __restrict__ in,
                             unsigned short* __restrict__ out) {
  int i4 = blockIdx.x * blockDim.x + threadIdx.x;
  const int RW = HIDDEN / 4;   // 768 int4-groups per row
  if (i4 >= 2 * INTER * RW) return;
  int rowp = i4 / RW;
  int col4 = i4 - rowp * RW;
  int c = ((rowp >> 5) << 4) + (rowp & 15);
  int u = (rowp >> 4) & 1;
  int srow = u * INTER + c;
  int4 v = reinterpret_cast<const int4*>(in)[(size_t)srow * RW + col4];
  ushort4 o;
  o.x = f2bf((float)v.x); o.y = f2bf((float)v.y);
  o.z = f2bf((float)v.z); o.w = f2bf((float)v.w);
  reinterpret_cast<ushort4*>(out)[i4] = o;
}

// ------- 256x256 GEMM, 16x16x32 MFMA, phase-pipelined fragments -------
// Round-10: every MFMA cluster consumes fragments read ONE PHASE EARLIER
// (register ping-pong aP/aQ, bP/bQ) so ds_reads always overlap the MFMA
// cluster with no RAW stall (the m201/HK mechanism we lacked; R9 measured
// reads+MFMA near-serial: wall 4700cy = LDS 2300 + MFMA 2483).
//
// Per tile t (parity pr), 4 phases, 2 barriers:
//  Ph0: reads aQ<-A(t,k0,h1); MFMA aP x bP -> acc[0..3]; stage A(t+1)k0
//  Ph1: vmcnt+BAR; reads aP<-A(t,k1,h0), bQ<-B(t,k1); MFMA aQ x bP ->
//       acc[4..7]; stage B(t+1)k0
//  Ph2: reads aQ<-A(t,k1,h1); MFMA aP x bQ -> acc[0..3]; stage A(t+1)k1
//       (no barrier: kh1 readiness was established at Ph1's barrier)
//  Ph3: vmcnt+BAR; reads aP<-A(t+1,k0,h0), bP<-B(t+1,k0) [skip at tail];
//       MFMA aQ x bQ -> acc[4..7]; stage B(t+1)k1
//
// vmcnt ledger (2 loads/stage; t+1 stage order Ak0@Ph0, Bk0@Ph1, Ak1@Ph2,
// Bk1@Ph3): Ph1-start outstanding {A(t)k1, B(t)k1, A(t+1)k0} = 6; need
// first two -> vmcnt(2); tail t==NT-1: only {A(t)k1,B(t)k1} -> vmcnt(0).
// Ph3-start outstanding {A(t+1)k0, B(t+1)k0, A(t+1)k1} = 6; need first
// two -> vmcnt(2); last tile: 0 outstanding, no-op.
// WAR audit: each LDS buffer's last reader precedes its next stager by
// >=1 barrier (k0 bufs: read Ph0, staged Ph0 next-next tile across Ph1/Ph3
// bars; k1 bufs: read Ph2/Ph3, staged Ph2 of next tile across Ph3 bar).
// Swizzle (VALIDATED R6, 0 conflicts): cb ^= (row>>1)&3 both sides.

template<int K, int N, int MODE>
__global__ __launch_bounds__(512, 2) void gemm8p(
    const unsigned short* __restrict__ A,   // [NTOK][K]
    const unsigned short* __restrict__ B,   // [N][K]
    const float* __restrict__ scale,
    void* __restrict__ outv)
{
  constexpr int NT = K / 64;
  __shared__ __align__(16) unsigned short lds[2][2][2][256 * 32];

  const int nbn = N / 256;
  const int nwg = (NTOK / 256) * nbn;       // %8 == 0 for both instantiations
  int bid = blockIdx.x;
  int wg = (bid & 7) * (nwg >> 3) + (bid >> 3);   // XCD-aware bijective swizzle
  const int bm = (wg / nbn) * 256;
  const int bn = (wg % nbn) * 256;

  const int tid  = threadIdx.x;
  const int lane = tid & 63;
  const int wid  = tid >> 6;
  const int wr = wid >> 2;                  // 0..1
  const int wc = wid & 3;                   // 0..3

  const int srow0 = tid >> 2;               // staging rows 0..127
  const int srow1 = 128 + (tid >> 2);       // staging rows 128..255
  const int scb   = tid & 3;

  const unsigned short* Ab = A + (size_t)bm * K;
  const unsigned short* Bb = B + (size_t)bn * K;

  auto stage = [&](const unsigned short* Gb, int op, int tt, int kh) {
    if (tt >= NT) return;
    int p = tt & 1;
    int kc = tt * 64 + kh * 32;
    unsigned short* lbase = &lds[p][op][kh][0];
    gload_lds16(Gb + (size_t)srow0 * K + kc + ((scb ^ ((srow0 >> 1) & 3)) * 8),
                lbase + (size_t)tid * 8);
    gload_lds16(Gb + (size_t)srow1 * K + kc + ((scb ^ ((srow1 >> 1) & 3)) * 8),
                lbase + (size_t)(512 + tid) * 8);
  };

  auto readA = [&](int p, int kh, int m) -> bf16x8 {
    int row = wr * 128 + m * 16 + (lane & 15);
    int cb = (lane >> 4) ^ ((row >> 1) & 3);
    return *(const bf16x8*)&lds[p][0][kh][row * 32 + cb * 8];
  };
  auto readB = [&](int p, int kh, int n) -> bf16x8 {
    int row = wc * 64 + n * 16 + (lane & 15);
    int cb = (lane >> 4) ^ ((row >> 1) & 3);
    return *(const bf16x8*)&lds[p][1][kh][row * 32 + cb * 8];
  };

  f32x4 acc[8][4] = {};
  bf16x8 aP[4], aQ[4], bP[4], bQ[4];

  // prologue: stage tile 0 (4 half-tiles); drain k0; preload aP/bP
  stage(Ab, 0, 0, 0);
  stage(Bb, 1, 0, 0);
  stage(Ab, 0, 0, 1);
  stage(Bb, 1, 0, 1);
  asm volatile("s_waitcnt vmcnt(4)" ::: "memory");
  __builtin_amdgcn_s_barrier();
#pragma unroll
  for (int m = 0; m < 4; ++m) aP[m] = readA(0, 0, m);
#pragma unroll
  for (int n = 0; n < 4; ++n) bP[n] = readB(0, 0, n);

  for (int t = 0; t < NT; ++t) {
    const int pr = t & 1;

    // ---- Ph0: MFMA k0/h0 (aP x bP); read A(t,k0,h1)->aQ ----
#pragma unroll
    for (int m = 0; m < 4; ++m) aQ[m] = readA(pr, 0, m + 4);
    stage(Ab, 0, t + 1, 0);
    __builtin_amdgcn_s_setprio(1);
#pragma unroll
    for (int m = 0; m < 4; ++m)
#pragma unroll
      for (int n = 0; n < 4; ++n)
        acc[m][n] = __builtin_amdgcn_mfma_f32_16x16x32_bf16(aP[m], bP[n], acc[m][n], 0, 0, 0);
    __builtin_amdgcn_s_setprio(0);

    // ---- Ph1: drain kh1(t); BAR; read A(t,k1,h0)->aP, B(t,k1)->bQ;
    //           MFMA k0/h1 (aQ x bP) ----
    if (t + 1 < NT) {
      asm volatile("s_waitcnt vmcnt(2)" ::: "memory");
    } else {
      asm volatile("s_waitcnt vmcnt(0)" ::: "memory");
    }
    __builtin_amdgcn_s_barrier();
#pragma unroll
    for (int m = 0; m < 4; ++m) aP[m] = readA(pr, 1, m);
#pragma unroll
    for (int n = 0; n < 4; ++n) bQ[n] = readB(pr, 1, n);
    stage(Bb, 1, t + 1, 0);
    __builtin_amdgcn_s_setprio(1);
#pragma unroll
    for (int m = 0; m < 4; ++m)
#pragma unroll
      for (int n = 0; n < 4; ++n)
        acc[m + 4][n] = __builtin_amdgcn_mfma_f32_16x16x32_bf16(aQ[m], bP[n], acc[m + 4][n], 0, 0, 0);
    __builtin_amdgcn_s_setprio(0);

    // ---- Ph2: read A(t,k1,h1)->aQ; MFMA k1/h0 (aP x bQ); no barrier ----
#pragma unroll
    for (int m = 0; m < 4; ++m) aQ[m] = readA(pr, 1, m + 4);
    stage(Ab, 0, t + 1, 1);
    __builtin_amdgcn_s_setprio(1);
#pragma unroll
    for (int m = 0; m < 4; ++m)
#pragma unroll
      for (int n = 0; n < 4; ++n)
        acc[m][n] = __builtin_amdgcn_mfma_f32_16x16x32_bf16(aP[m], bQ[n], acc[m][n], 0, 0, 0);
    __builtin_amdgcn_s_setprio(0);

    // ---- Ph3: drain k0(t+1); BAR; read A(t+1,k0,h0)->aP, B(t+1,k0)->bP;
    //           MFMA k1/h1 (aQ x bQ) ----
    asm volatile("s_waitcnt vmcnt(2)" ::: "memory");
    __builtin_amdgcn_s_barrier();
    if (t + 1 < NT) {
#pragma unroll
      for (int m = 0; m < 4; ++m) aP[m] = readA(pr ^ 1, 0, m);
#pragma unroll
      for (int n = 0; n < 4; ++n) bP[n] = readB(pr ^ 1, 0, n);
    }
    stage(Bb, 1, t + 1, 1);
    __builtin_amdgcn_s_setprio(1);
#pragma unroll
    for (int m = 0; m < 4; ++m)
#pragma unroll
      for (int n = 0; n < 4; ++n)
        acc[m + 4][n] = __builtin_amdgcn_mfma_f32_16x16x32_bf16(aQ[m], bQ[n], acc[m + 4][n], 0, 0, 0);
    __builtin_amdgcn_s_setprio(0);
  }

  // ---- epilogue: C/D layout col=lane&15, row=(lane>>4)*4+j ----
  const int crow0 = (lane >> 4) * 4;
  const int ccol  = lane & 15;
  if constexpr (MODE == 1) {
    // SwiGLU: n-frags (gate,up,gate,up) via 16-granular W interleave
    unsigned short* H = (unsigned short*)outv;     // [NTOK][INTER]
    const int hbase = (bn >> 1) + wc * 32;
#pragma unroll
    for (int np = 0; np < 2; ++np) {
      int hcol = hbase + np * 16 + ccol;
      float sg = scale[hcol];
      float su = scale[INTER + hcol];
#pragma unroll
      for (int m = 0; m < 8; ++m) {
#pragma unroll
        for (int j = 0; j < 4; ++j) {
          int row = bm + wr * 128 + m * 16 + crow0 + j;
          float g = acc[m][2 * np + 0][j] * sg;
          float u = acc[m][2 * np + 1][j] * su;
          float s = g / (1.0f + __expf(-g));       // silu
          H[(size_t)row * INTER + hcol] = f2bf(u * s);
        }
      }
    }
  } else {
    float* O = (float*)outv;                       // [NTOK][N]
#pragma unroll
    for (int n = 0; n < 4; ++n) {
      int col = bn + wc * 64 + n * 16 + ccol;
      float sc = scale[col];
#pragma unroll
      for (int m = 0; m < 8; ++m) {
#pragma unroll
        for (int j = 0; j < 4; ++j) {
          int row = bm + wr * 128 + m * 16 + crow0 + j;
          O[(size_t)row * N + col] = acc[m][n][j] * sc;
        }
      }
    }
  }
}

// ---------------- launch ----------------

extern "C" void kernel_launch(void* const* d_in, const int* in_sizes, int n_in,
                              void* d_out, int out_size, void* d_ws, size_t ws_size,
                              hipStream_t stream) {
  (void)in_sizes; (void)n_in; (void)out_size; (void)ws_size;

  const float* hidden = (const float*)d_in[0];   // [NTOK][HIDDEN] f32
  const int*   guq    = (const int*)d_in[1];     // [2*INTER][HIDDEN] i32
  const float* gus    = (const float*)d_in[2];   // [2*INTER]
  const int*   dwq    = (const int*)d_in[3];     // [HIDDEN][INTER] i32
  const float* dsc    = (const float*)d_in[4];   // [HIDDEN]
  float* out = (float*)d_out;

  char* ws = (char*)d_ws;
  unsigned short* xb  = (unsigned short*)(ws);                      // 50,331,648 B
  unsigned short* wgu = (unsigned short*)(ws + 50331648ull);        // 100,663,296 B (permuted)
  unsigned short* wd  = (unsigned short*)(ws + 150994944ull);       // 50,331,648 B
  unsigned short* hb  = (unsigned short*)(ws + 201326592ull);       // 134,217,728 B
  // total ws use: 335,544,320 B

  {
    int n4 = NTOK * HIDDEN / 4;
    cvt_f32_bf16<<<(n4 + 255) / 256, 256, 0, stream>>>(hidden, xb, n4);
  }
  {
    int n4 = 2 * INTER * HIDDEN / 4;
    cvt_wgu_perm<<<(n4 + 255) / 256, 256, 0, stream>>>(guq, wgu);
  }
  {
    int n4 = HIDDEN * INTER / 4;
    cvt_i32_bf16<<<(n4 + 255) / 256, 256, 0, stream>>>(dwq, wd, n4);
  }

  // GEMM1+SwiGLU: [8192 x 16384] over K=3072, writes H bf16 [8192][8192]
  gemm8p<HIDDEN, 2 * INTER, 1>
      <<<(NTOK / 256) * (2 * INTER / 256), 512, 0, stream>>>(xb, wgu, gus, hb);
  // GEMM2: [8192 x 3072] over K=8192, full-K, plain f32 store
  gemm8p<INTER, HIDDEN, 2>
      <<<(NTOK / 256) * (HIDDEN / 256), 512, 0, stream>>>(hb, wd, dsc, out);
}